// Round 2
// baseline (6098.967 us; speedup 1.0000x reference)
//
#include <hip/hip_runtime.h>
#include <hip/hip_bf16.h>

#define BB   4
#define CIN  64
#define COUT 128
#define HH   512
#define WW   512
#define BSZ  32
#define NBLK 512
#define NCELL 1024

// ---- workspace layout (floats) ----
// map   : int[1024]           @ 0
// w1f   : [128][64]           @ 1024
// wdf   : [128][64]           @ 9216
// w3f   : [128][128]          @ 17408
// w2f   : [128][128][3][3]    @ 33792
// bias  : [4][128] (b1,b2,b3,bd) @ 181248
#define WS_W1F  1024
#define WS_WDF  9216
#define WS_W3F  17408
#define WS_W2F  33792
#define WS_BIAS 181248

__global__ void k_prep(
    const float* __restrict__ w1, const float* __restrict__ b1,
    const float* __restrict__ w2, const float* __restrict__ b2,
    const float* __restrict__ w3, const float* __restrict__ b3,
    const float* __restrict__ wd, const float* __restrict__ bd,
    const float* __restrict__ g1, const float* __restrict__ be1, const float* __restrict__ m1, const float* __restrict__ v1,
    const float* __restrict__ g2, const float* __restrict__ be2, const float* __restrict__ m2, const float* __restrict__ v2,
    const float* __restrict__ g3, const float* __restrict__ be3, const float* __restrict__ m3, const float* __restrict__ v3,
    float* __restrict__ ws)
{
    int idx = blockIdx.x * 256 + threadIdx.x;
    int* map = (int*)ws;

    if (idx < NCELL) map[idx] = -1;

    if (idx < COUT * CIN) {      // 8192: w1f (BN-folded) and wdf
        int o = idx / CIN;
        float s = g1[o] * rsqrtf(v1[o] + 1e-5f);
        ws[WS_W1F + idx] = w1[idx] * s;
        ws[WS_WDF + idx] = wd[idx];
    }
    if (idx < COUT * COUT) {     // 16384: w3f
        int o = idx / COUT;
        float s = g3[o] * rsqrtf(v3[o] + 1e-5f);
        ws[WS_W3F + idx] = w3[idx] * s;
    }
    if (idx < COUT * COUT * 9) { // 147456: w2f
        int o = idx / (COUT * 9);
        float s = g2[o] * rsqrtf(v2[o] + 1e-5f);
        ws[WS_W2F + idx] = w2[idx] * s;
    }
    if (idx < COUT) {            // folded biases
        float s1 = g1[idx] * rsqrtf(v1[idx] + 1e-5f);
        ws[WS_BIAS + idx]       = (b1[idx] - m1[idx]) * s1 + be1[idx];
        float s2 = g2[idx] * rsqrtf(v2[idx] + 1e-5f);
        ws[WS_BIAS + 128 + idx] = (b2[idx] - m2[idx]) * s2 + be2[idx];
        float s3 = g3[idx] * rsqrtf(v3[idx] + 1e-5f);
        ws[WS_BIAS + 256 + idx] = (b3[idx] - m3[idx]) * s3 + be3[idx];
        ws[WS_BIAS + 384 + idx] = bd[idx];
    }
}

__global__ void k_map(const int* __restrict__ ind, int* __restrict__ map)
{
    int i = threadIdx.x;  // 512
    int f = ind[i * 3] * 256 + ind[i * 3 + 1] * 16 + ind[i * 3 + 2];
    map[f] = 1;
}

// One workgroup (512 threads = 8 waves) per active block.
// Rolling 4-row t1 buffer; processes output rows in pairs.
__global__ __launch_bounds__(512)
void k_main(const float* __restrict__ x, const int* __restrict__ ind,
            const float* __restrict__ ws, float* __restrict__ out)
{
    __shared__ float t1r[4][COUT][BSZ + 2];            // 69632 B (halo-padded cols)
    __shared__ float t2s[2][COUT][BSZ];                // 32768 B
    __shared__ __align__(16) float xbr[4][CIN][BSZ];   // 32768 B

    const float* w1f  = ws + WS_W1F;
    const float* wdf  = ws + WS_WDF;
    const float* w3f  = ws + WS_W3F;
    const float* w2f  = ws + WS_W2F;
    const float* bias = ws + WS_BIAS;

    const int blk = blockIdx.x;
    const int bi = ind[blk * 3 + 0];
    const int gy = ind[blk * 3 + 1];
    const int gx = ind[blk * 3 + 2];

    const int tid  = threadIdx.x;
    const int lx   = tid & 31;
    const int half = (tid >> 5) & 1;
    const int ob   = __builtin_amdgcn_readfirstlane((tid >> 6) * 16);  // wave's o-base (SGPR)

    const size_t HW = (size_t)HH * WW;
    const float* xb = x   + (size_t)bi * CIN  * HW + (size_t)(gy * BSZ) * WW + (size_t)(gx * BSZ);
    float*       op = out + (size_t)bi * COUT * HW + (size_t)(gy * BSZ) * WW + (size_t)(gx * BSZ);

    // zero halo columns of t1r (stay zero forever)
    for (int i = tid; i < 4 * COUT; i += 512) {
        t1r[i >> 7][i & 127][0]       = 0.f;
        t1r[i >> 7][i & 127][BSZ + 1] = 0.f;
    }

    // stage x rows r0, r0+1 into xbr slots (zeros outside block)
    auto stage2 = [&](int r0) {
#pragma unroll
        for (int j = 0; j < 2; ++j) {
            int q = tid + j * 512;           // 0..1023 = 2 rows * 64c * 8 quads
            int r = r0 + (q >> 9);
            int rem = q & 511;
            int c = rem >> 3, xq = (rem & 7) << 2;
            float4 val = make_float4(0.f, 0.f, 0.f, 0.f);
            if (r >= 0 && r < BSZ)
                val = *(const float4*)(xb + (size_t)c * HW + (size_t)r * WW + xq);
            *(float4*)&xbr[r & 3][c][xq] = val;
        }
    };

    // conv1 + bn1 + relu for rows r0, r0+1 (lane's row = r0+half); zero if out of range
    auto t1_rows = [&](int r0) {
        int r = r0 + half;
        int slot = r & 3;
        float acc[16];
#pragma unroll
        for (int k = 0; k < 16; ++k) acc[k] = 0.f;
        for (int c = 0; c < CIN; ++c) {
            float xv = xbr[slot][c][lx];
#pragma unroll
            for (int k = 0; k < 16; ++k)
                acc[k] = fmaf(w1f[(ob + k) * CIN + c], xv, acc[k]);
        }
        bool valid = (r >= 0) && (r < BSZ);
#pragma unroll
        for (int k = 0; k < 16; ++k) {
            float v = acc[k] + bias[ob + k];
            t1r[slot][ob + k][1 + lx] = valid ? fmaxf(v, 0.f) : 0.f;
        }
    };

    // prologue: rows -1 (zeros) and 0
    stage2(-1);
    __syncthreads();
    t1_rows(-1);
    __syncthreads();

    for (int p = 0; p < 16; ++p) {
        stage2(2 * p + 1);          // rows 2p+1, 2p+2
        __syncthreads();
        t1_rows(2 * p + 1);
        __syncthreads();

        // ---- conv2 (3x3) + bn2 + relu for rows 2p, 2p+1 ----
        {
            int row = 2 * p + half;
            int sm = (row - 1) & 3, s0 = row & 3, sp = (row + 1) & 3;
            float acc[16];
#pragma unroll
            for (int k = 0; k < 16; ++k) acc[k] = 0.f;
            for (int c = 0; c < COUT; ++c) {
                float v00 = t1r[sm][c][lx], v01 = t1r[sm][c][lx + 1], v02 = t1r[sm][c][lx + 2];
                float v10 = t1r[s0][c][lx], v11 = t1r[s0][c][lx + 1], v12 = t1r[s0][c][lx + 2];
                float v20 = t1r[sp][c][lx], v21 = t1r[sp][c][lx + 1], v22 = t1r[sp][c][lx + 2];
                const float* wp = w2f + (size_t)(ob * COUT + c) * 9;
#pragma unroll
                for (int k = 0; k < 16; ++k) {
                    const float* w = wp + (size_t)k * COUT * 9;
                    acc[k] = fmaf(w[0], v00, acc[k]);
                    acc[k] = fmaf(w[1], v01, acc[k]);
                    acc[k] = fmaf(w[2], v02, acc[k]);
                    acc[k] = fmaf(w[3], v10, acc[k]);
                    acc[k] = fmaf(w[4], v11, acc[k]);
                    acc[k] = fmaf(w[5], v12, acc[k]);
                    acc[k] = fmaf(w[6], v20, acc[k]);
                    acc[k] = fmaf(w[7], v21, acc[k]);
                    acc[k] = fmaf(w[8], v22, acc[k]);
                }
            }
#pragma unroll
            for (int k = 0; k < 16; ++k)
                t2s[half][ob + k][lx] = fmaxf(acc[k] + bias[128 + ob + k], 0.f);
        }
        __syncthreads();

        // ---- conv3 + bn3 + relu, downsample, store ----
        {
            int row = 2 * p + half;
            int sx = row & 3;
            float a3[16], ay[16];
#pragma unroll
            for (int k = 0; k < 16; ++k) { a3[k] = 0.f; ay[k] = 0.f; }
            for (int c = 0; c < COUT; ++c) {
                float tv = t2s[half][c][lx];
#pragma unroll
                for (int k = 0; k < 16; ++k)
                    a3[k] = fmaf(w3f[(ob + k) * COUT + c], tv, a3[k]);
            }
            for (int c = 0; c < CIN; ++c) {
                float xv = xbr[sx][c][lx];
#pragma unroll
                for (int k = 0; k < 16; ++k)
                    ay[k] = fmaf(wdf[(ob + k) * CIN + c], xv, ay[k]);
            }
#pragma unroll
            for (int k = 0; k < 16; ++k) {
                float v3 = fmaxf(a3[k] + bias[256 + ob + k], 0.f);
                float ov = v3 + ay[k] + bias[384 + ob + k];
                op[(size_t)(ob + k) * HW + (size_t)row * WW + lx] = ov;
            }
        }
        __syncthreads();
    }
}

// downsample-only for inactive cells; one WG (256 threads) per cell
__global__ __launch_bounds__(256)
void k_inactive(const float* __restrict__ x, const float* __restrict__ ws,
                float* __restrict__ out)
{
    __shared__ __align__(16) float xs[2][CIN][BSZ];

    const int* map = (const int*)ws;
    const float* wdf  = ws + WS_WDF;
    const float* bias = ws + WS_BIAS;

    int cell = blockIdx.x;
    if (map[cell] > 0) return;   // active cell handled by k_main

    int bi = cell >> 8;
    int gy = (cell >> 4) & 15;
    int gx = cell & 15;

    const int tid  = threadIdx.x;
    const int lx   = tid & 31;
    const int yoff = (tid >> 5) & 1;
    const int ob   = __builtin_amdgcn_readfirstlane((tid >> 6) * 32);

    const size_t HW = (size_t)HH * WW;
    const float* xb = x   + (size_t)bi * CIN  * HW + (size_t)(gy * BSZ) * WW + (size_t)(gx * BSZ);
    float*       op = out + (size_t)bi * COUT * HW + (size_t)(gy * BSZ) * WW + (size_t)(gx * BSZ);

    for (int y0 = 0; y0 < BSZ; y0 += 2) {
#pragma unroll
        for (int j = 0; j < 4; ++j) {
            int q = tid + j * 256;           // 2 rows * 64c * 8 quads = 1024
            int r = q >> 9, rem = q & 511;
            int c = rem >> 3, xq = (rem & 7) << 2;
            *(float4*)&xs[r][c][xq] =
                *(const float4*)(xb + (size_t)c * HW + (size_t)(y0 + r) * WW + xq);
        }
        __syncthreads();

        float acc[32];
#pragma unroll
        for (int k = 0; k < 32; ++k) acc[k] = 0.f;
        for (int c = 0; c < CIN; ++c) {
            float xv = xs[yoff][c][lx];
#pragma unroll
            for (int k = 0; k < 32; ++k)
                acc[k] = fmaf(wdf[(ob + k) * CIN + c], xv, acc[k]);
        }
        int row = y0 + yoff;
#pragma unroll
        for (int k = 0; k < 32; ++k)
            op[(size_t)(ob + k) * HW + (size_t)row * WW + lx] = acc[k] + bias[384 + ob + k];
        __syncthreads();
    }
}

extern "C" void kernel_launch(void* const* d_in, const int* in_sizes, int n_in,
                              void* d_out, int out_size, void* d_ws, size_t ws_size,
                              hipStream_t stream)
{
    const float* x   = (const float*)d_in[0];
    const int*   ind = (const int*)d_in[1];
    const float* w1  = (const float*)d_in[2];
    const float* b1  = (const float*)d_in[3];
    const float* w2  = (const float*)d_in[4];
    const float* b2  = (const float*)d_in[5];
    const float* w3  = (const float*)d_in[6];
    const float* b3  = (const float*)d_in[7];
    const float* wd  = (const float*)d_in[8];
    const float* bd  = (const float*)d_in[9];
    const float* g1  = (const float*)d_in[10];
    const float* be1 = (const float*)d_in[11];
    const float* m1  = (const float*)d_in[12];
    const float* v1  = (const float*)d_in[13];
    const float* g2  = (const float*)d_in[14];
    const float* be2 = (const float*)d_in[15];
    const float* m2  = (const float*)d_in[16];
    const float* v2  = (const float*)d_in[17];
    const float* g3  = (const float*)d_in[18];
    const float* be3 = (const float*)d_in[19];
    const float* m3  = (const float*)d_in[20];
    const float* v3  = (const float*)d_in[21];

    float* ws  = (float*)d_ws;
    float* out = (float*)d_out;

    hipLaunchKernelGGL(k_prep, dim3(576), dim3(256), 0, stream,
                       w1, b1, w2, b2, w3, b3, wd, bd,
                       g1, be1, m1, v1, g2, be2, m2, v2, g3, be3, m3, v3, ws);
    hipLaunchKernelGGL(k_map, dim3(1), dim3(NBLK), 0, stream, ind, (int*)d_ws);
    hipLaunchKernelGGL(k_main, dim3(NBLK), dim3(512), 0, stream, x, ind, ws, out);
    hipLaunchKernelGGL(k_inactive, dim3(NCELL), dim3(256), 0, stream, x, ws, out);
}

// Round 3
// 1388.397 us; speedup vs baseline: 4.3928x; 4.3928x over previous
//
#include <hip/hip_runtime.h>
#include <hip/hip_bf16.h>

#define BB    4
#define CIN   64
#define COUT  128
#define HH    512
#define WW    512
#define BSZ   32
#define NBLK  512
#define NCELL 1024

typedef unsigned short u16;
typedef unsigned int   u32;
typedef __attribute__((ext_vector_type(8))) short bf8_t;   // 8 bf16 (4 VGPRs)
typedef __attribute__((ext_vector_type(4))) float f32x4;

#define MFMA(a, b, c) __builtin_amdgcn_mfma_f32_16x16x32_bf16((a), (b), (c), 0, 0, 0)

// swizzled byte offset inside a row-tile; px-major, channel-contiguous
// stride-256B rows (t1 / t2: 128 ch * 2B)
#define SWZ256(px, k2) (((((px) << 8) + ((k2) << 1))) ^ (((px) & 7) << 4))
// stride-128B rows (xs: 64 ch * 2B)
#define SWZ128(px, k2) (((((px) << 7) + ((k2) << 1))) ^ (((px) & 7) << 4))

__device__ __forceinline__ u16 f2bf(float f) {
    u32 x = __float_as_uint(f);
    u32 r = x + 0x7fffu + ((x >> 16) & 1u);   // RNE
    return (u16)(r >> 16);
}
__device__ __forceinline__ uint2 pack4(float a, float b, float c, float d) {
    return make_uint2((u32)f2bf(a) | ((u32)f2bf(b) << 16),
                      (u32)f2bf(c) | ((u32)f2bf(d) << 16));
}

// ---- workspace layout (bytes) ----
// map    int[1024]              @ 0
// biasf  float[4][128]          @ 4096   (b1,b2,b3,bd folded)
// w1bf   u16[128][64]           @ 8192
// wdbf   u16[128][64]           @ 24576
// w3bf   u16[128][128]          @ 40960
// w2bf   u16[9][128][128]       @ 73728  (tap-major, BN2-folded)

__global__ void k_prep(const float* __restrict__ w1, const float* __restrict__ b1,
                       const float* __restrict__ w2, const float* __restrict__ b2,
                       const float* __restrict__ w3, const float* __restrict__ b3,
                       const float* __restrict__ wd, const float* __restrict__ bd,
                       const float* __restrict__ g1, const float* __restrict__ be1,
                       const float* __restrict__ m1, const float* __restrict__ v1,
                       const float* __restrict__ g2, const float* __restrict__ be2,
                       const float* __restrict__ m2, const float* __restrict__ v2,
                       const float* __restrict__ g3, const float* __restrict__ be3,
                       const float* __restrict__ m3, const float* __restrict__ v3,
                       void* wsv)
{
    int idx = blockIdx.x * 256 + threadIdx.x;
    int*   map   = (int*)wsv;
    float* biasf = (float*)((char*)wsv + 4096);
    u16*   w1bf  = (u16*)((char*)wsv + 8192);
    u16*   wdbf  = (u16*)((char*)wsv + 24576);
    u16*   w3bf  = (u16*)((char*)wsv + 40960);
    u16*   w2bf  = (u16*)((char*)wsv + 73728);

    if (idx < NCELL) map[idx] = -1;
    if (idx < 128) {
        float s1 = g1[idx] * rsqrtf(v1[idx] + 1e-5f);
        biasf[idx]       = (b1[idx] - m1[idx]) * s1 + be1[idx];
        float s2 = g2[idx] * rsqrtf(v2[idx] + 1e-5f);
        biasf[128 + idx] = (b2[idx] - m2[idx]) * s2 + be2[idx];
        float s3 = g3[idx] * rsqrtf(v3[idx] + 1e-5f);
        biasf[256 + idx] = (b3[idx] - m3[idx]) * s3 + be3[idx];
        biasf[384 + idx] = bd[idx];
    }
    if (idx < 8192) {          // [o][c] 128x64
        int o = idx >> 6;
        float s = g1[o] * rsqrtf(v1[o] + 1e-5f);
        w1bf[idx] = f2bf(w1[idx] * s);
        wdbf[idx] = f2bf(wd[idx]);
    }
    if (idx < 16384) {         // [o][c] 128x128
        int o = idx >> 7;
        float s = g3[o] * rsqrtf(v3[o] + 1e-5f);
        w3bf[idx] = f2bf(w3[idx] * s);
    }
    if (idx < 147456) {        // [tap][o][c]
        int tap = idx >> 14, rem = idx & 16383;
        int o = rem >> 7, c = rem & 127;
        float s = g2[o] * rsqrtf(v2[o] + 1e-5f);
        w2bf[idx] = f2bf(w2[(o * 128 + c) * 9 + tap] * s);
    }
}

__global__ void k_map(const int* __restrict__ ind, int* __restrict__ map)
{
    int i = threadIdx.x;  // 512
    int f = ind[i * 3] * 256 + ind[i * 3 + 1] * 16 + ind[i * 3 + 2];
    map[f] = 1;
}

// One 512-thread workgroup (8 waves) per active block; MFMA pipeline.
__global__ __launch_bounds__(512)
void k_main(const float* __restrict__ x, const int* __restrict__ ind,
            const void* __restrict__ wsv, float* __restrict__ out)
{
    __shared__ __align__(16) u16 t1s[8][34 * 128];   // 69632 B (px' 0..33 halo, swizzled)
    __shared__ __align__(16) u16 t2ss[4][32 * 128];  // 32768 B
    __shared__ __align__(16) u16 xss[8][32 * 64];    // 32768 B
    __shared__ __align__(16) float bias_s[512];      //  2048 B

    const float* biasf = (const float*)((const char*)wsv + 4096);
    const u16*   w1bf  = (const u16*)((const char*)wsv + 8192);
    const u16*   wdbf  = (const u16*)((const char*)wsv + 24576);
    const u16*   w3bf  = (const u16*)((const char*)wsv + 40960);
    const u16*   w2bf  = (const u16*)((const char*)wsv + 73728);

    const int blk = blockIdx.x;
    const int bi = ind[blk * 3 + 0];
    const int gy = ind[blk * 3 + 1];
    const int gx = ind[blk * 3 + 2];

    const int tid  = threadIdx.x;
    const int lane = tid & 63;
    const int wid  = tid >> 6;        // 0..7
    const int lcol = lane & 15;       // MFMA col / A-row index
    const int lrow = lane >> 4;       // 0..3
    const int cb   = (wid >> 2) * 64; // cout half for conv2/3/ds
    const int wr   = wid & 3;         // row-within-iter for conv2/3/ds

    const size_t HW = (size_t)HH * WW;
    const float* xb = x   + (size_t)bi * CIN  * HW + (size_t)(gy * BSZ) * WW + (size_t)(gx * BSZ);
    float*       op = out + (size_t)bi * COUT * HW + (size_t)(gy * BSZ) * WW + (size_t)(gx * BSZ);

    const f32x4 zero4 = {0.f, 0.f, 0.f, 0.f};

    // stage 4 consecutive x rows (r0..r0+3) into xss ring as bf16 [px][cin]
    auto stage4 = [&](int r0) {
        if (r0 >= 32) return;
        const int px = tid & 31, chq = (tid >> 5) & 15;
#pragma unroll
        for (int j = 0; j < 4; ++j) {
            const int r = r0 + j;
            const float* sp = xb + (size_t)(chq * 4) * HW + (size_t)r * WW + px;
            float v0 = sp[0], v1 = sp[HW], v2 = sp[2 * HW], v3 = sp[3 * HW];
            *(uint2*)((char*)xss[r & 7] + SWZ128(px, chq * 4)) = pack4(v0, v1, v2, v3);
        }
    };

    // conv1 + bn1 + relu for one row -> t1 ring (bf16, halo'd, swizzled)
    auto conv1_row = [&](int r) {
        if (r > 32) return;
        f32x4 acc0 = zero4, acc1 = zero4;
        if (r < 32) {
            const char* xrow = (const char*)xss[r & 7];
#pragma unroll
            for (int ks = 0; ks < 2; ++ks) {
                const int kb = ks * 32 + lrow * 8;
                bf8_t a  = *(const bf8_t*)(w1bf + (wid * 16 + lcol) * 64 + kb);
                bf8_t b0 = *(const bf8_t*)(xrow + SWZ128(lcol, kb));
                bf8_t b1 = *(const bf8_t*)(xrow + SWZ128(lcol + 16, kb));
                acc0 = MFMA(a, b0, acc0);
                acc1 = MFMA(a, b1, acc1);
            }
        }
        char* trow = (char*)t1s[r & 7];
        const int ch = wid * 16 + lrow * 4;
        uint2 p0, p1;
        if (r < 32) {
            f32x4 bv = *(const f32x4*)&bias_s[ch];
            p0 = pack4(fmaxf(acc0[0] + bv[0], 0.f), fmaxf(acc0[1] + bv[1], 0.f),
                       fmaxf(acc0[2] + bv[2], 0.f), fmaxf(acc0[3] + bv[3], 0.f));
            p1 = pack4(fmaxf(acc1[0] + bv[0], 0.f), fmaxf(acc1[1] + bv[1], 0.f),
                       fmaxf(acc1[2] + bv[2], 0.f), fmaxf(acc1[3] + bv[3], 0.f));
        } else {
            p0 = make_uint2(0u, 0u); p1 = p0;
        }
        *(uint2*)(trow + SWZ256(lcol + 1, ch))  = p0;
        *(uint2*)(trow + SWZ256(lcol + 17, ch)) = p1;
    };

    // ---- prologue ----
    for (int i = tid; i < 17408; i += 512) ((u32*)t1s)[i] = 0u;   // zero t1 ring (halo + row -1)
    if (tid < 512) bias_s[tid] = biasf[tid];
    stage4(0); stage4(4);
    __syncthreads();
    conv1_row(0); conv1_row(1); conv1_row(2);

    for (int p = 0; p < 8; ++p) {
        const int y = 4 * p + wr;

        // ---- phase 1: conv1 rows 4p+3, 4p+4 ----
        conv1_row(4 * p + 3);
        conv1_row(4 * p + 4);
        __syncthreads();

        // ---- phase 2: conv2 (3x3) + downsample GEMM ----
        f32x4 c2[4][2];
#pragma unroll
        for (int m = 0; m < 4; ++m) { c2[m][0] = zero4; c2[m][1] = zero4; }
#pragma unroll
        for (int tap = 0; tap < 9; ++tap) {
            const int dy = tap / 3 - 1, dx = tap % 3 - 1;
            const char* trow = (const char*)t1s[(y + dy) & 7];
            const u16* wt = w2bf + tap * 16384;
#pragma unroll
            for (int ks = 0; ks < 4; ++ks) {
                const int kb = ks * 32 + lrow * 8;
                bf8_t a0 = *(const bf8_t*)(wt + (cb + 0  + lcol) * 128 + kb);
                bf8_t a1 = *(const bf8_t*)(wt + (cb + 16 + lcol) * 128 + kb);
                bf8_t a2 = *(const bf8_t*)(wt + (cb + 32 + lcol) * 128 + kb);
                bf8_t a3 = *(const bf8_t*)(wt + (cb + 48 + lcol) * 128 + kb);
                bf8_t b0 = *(const bf8_t*)(trow + SWZ256(lcol + dx + 1, kb));
                bf8_t b1 = *(const bf8_t*)(trow + SWZ256(lcol + 16 + dx + 1, kb));
                c2[0][0] = MFMA(a0, b0, c2[0][0]);  c2[0][1] = MFMA(a0, b1, c2[0][1]);
                c2[1][0] = MFMA(a1, b0, c2[1][0]);  c2[1][1] = MFMA(a1, b1, c2[1][1]);
                c2[2][0] = MFMA(a2, b0, c2[2][0]);  c2[2][1] = MFMA(a2, b1, c2[2][1]);
                c2[3][0] = MFMA(a3, b0, c2[3][0]);  c2[3][1] = MFMA(a3, b1, c2[3][1]);
            }
        }
        // downsample GEMM (K=64) for the same row
        f32x4 cd[4][2];
#pragma unroll
        for (int m = 0; m < 4; ++m) { cd[m][0] = zero4; cd[m][1] = zero4; }
        {
            const char* xrow = (const char*)xss[y & 7];
#pragma unroll
            for (int ks = 0; ks < 2; ++ks) {
                const int kb = ks * 32 + lrow * 8;
                bf8_t a0 = *(const bf8_t*)(wdbf + (cb + 0  + lcol) * 64 + kb);
                bf8_t a1 = *(const bf8_t*)(wdbf + (cb + 16 + lcol) * 64 + kb);
                bf8_t a2 = *(const bf8_t*)(wdbf + (cb + 32 + lcol) * 64 + kb);
                bf8_t a3 = *(const bf8_t*)(wdbf + (cb + 48 + lcol) * 64 + kb);
                bf8_t b0 = *(const bf8_t*)(xrow + SWZ128(lcol, kb));
                bf8_t b1 = *(const bf8_t*)(xrow + SWZ128(lcol + 16, kb));
                cd[0][0] = MFMA(a0, b0, cd[0][0]);  cd[0][1] = MFMA(a0, b1, cd[0][1]);
                cd[1][0] = MFMA(a1, b0, cd[1][0]);  cd[1][1] = MFMA(a1, b1, cd[1][1]);
                cd[2][0] = MFMA(a2, b0, cd[2][0]);  cd[2][1] = MFMA(a2, b1, cd[2][1]);
                cd[3][0] = MFMA(a3, b0, cd[3][0]);  cd[3][1] = MFMA(a3, b1, cd[3][1]);
            }
        }
        // bn2 + relu -> t2 (bf16, swizzled)
        {
            char* t2row = (char*)t2ss[wr];
#pragma unroll
            for (int m = 0; m < 4; ++m) {
                const int ch = cb + m * 16 + lrow * 4;
                f32x4 bv = *(const f32x4*)&bias_s[128 + ch];
#pragma unroll
                for (int nt = 0; nt < 2; ++nt) {
                    uint2 pk = pack4(fmaxf(c2[m][nt][0] + bv[0], 0.f),
                                     fmaxf(c2[m][nt][1] + bv[1], 0.f),
                                     fmaxf(c2[m][nt][2] + bv[2], 0.f),
                                     fmaxf(c2[m][nt][3] + bv[3], 0.f));
                    *(uint2*)(t2row + SWZ256(nt * 16 + lcol, ch)) = pk;
                }
            }
        }
        __syncthreads();

        // ---- phase 3: conv3 + bn3 + relu + ds + store; conv1 rows 4p+5,4p+6; stage x ----
        {
            f32x4 c3[4][2];
#pragma unroll
            for (int m = 0; m < 4; ++m) { c3[m][0] = zero4; c3[m][1] = zero4; }
            const char* t2row = (const char*)t2ss[wr];
#pragma unroll
            for (int ks = 0; ks < 4; ++ks) {
                const int kb = ks * 32 + lrow * 8;
                bf8_t a0 = *(const bf8_t*)(w3bf + (cb + 0  + lcol) * 128 + kb);
                bf8_t a1 = *(const bf8_t*)(w3bf + (cb + 16 + lcol) * 128 + kb);
                bf8_t a2 = *(const bf8_t*)(w3bf + (cb + 32 + lcol) * 128 + kb);
                bf8_t a3 = *(const bf8_t*)(w3bf + (cb + 48 + lcol) * 128 + kb);
                bf8_t b0 = *(const bf8_t*)(t2row + SWZ256(lcol, kb));
                bf8_t b1 = *(const bf8_t*)(t2row + SWZ256(lcol + 16, kb));
                c3[0][0] = MFMA(a0, b0, c3[0][0]);  c3[0][1] = MFMA(a0, b1, c3[0][1]);
                c3[1][0] = MFMA(a1, b0, c3[1][0]);  c3[1][1] = MFMA(a1, b1, c3[1][1]);
                c3[2][0] = MFMA(a2, b0, c3[2][0]);  c3[2][1] = MFMA(a2, b1, c3[2][1]);
                c3[3][0] = MFMA(a3, b0, c3[3][0]);  c3[3][1] = MFMA(a3, b1, c3[3][1]);
            }
#pragma unroll
            for (int m = 0; m < 4; ++m) {
                const int ch = cb + m * 16 + lrow * 4;
                f32x4 bv3 = *(const f32x4*)&bias_s[256 + ch];
                f32x4 bvd = *(const f32x4*)&bias_s[384 + ch];
#pragma unroll
                for (int nt = 0; nt < 2; ++nt) {
#pragma unroll
                    for (int j = 0; j < 4; ++j) {
                        float val = fmaxf(c3[m][nt][j] + bv3[j], 0.f) + cd[m][nt][j] + bvd[j];
                        op[(size_t)(ch + j) * HW + (size_t)y * WW + nt * 16 + lcol] = val;
                    }
                }
            }
        }
        conv1_row(4 * p + 5);
        conv1_row(4 * p + 6);
        stage4(4 * p + 8);
        __syncthreads();
    }
}

// downsample-only for inactive cells (MFMA); one 512-thread WG per cell
__global__ __launch_bounds__(512)
void k_inactive(const float* __restrict__ x, const void* __restrict__ wsv,
                float* __restrict__ out)
{
    const int* map = (const int*)wsv;
    int cell = blockIdx.x;
    if (map[cell] > 0) return;

    __shared__ __align__(16) u16 xs2[4][32 * 64];   // 16 KB
    __shared__ __align__(16) float bds[128];

    const float* biasf = (const float*)((const char*)wsv + 4096);
    const u16*   wdbf  = (const u16*)((const char*)wsv + 24576);

    int bi = cell >> 8;
    int gy = (cell >> 4) & 15;
    int gx = cell & 15;

    const int tid  = threadIdx.x;
    const int lane = tid & 63;
    const int wid  = tid >> 6;
    const int lcol = lane & 15;
    const int lrow = lane >> 4;
    const int cb   = (wid >> 2) * 64;
    const int wr   = wid & 3;

    const size_t HW = (size_t)HH * WW;
    const float* xb = x   + (size_t)bi * CIN  * HW + (size_t)(gy * BSZ) * WW + (size_t)(gx * BSZ);
    float*       op = out + (size_t)bi * COUT * HW + (size_t)(gy * BSZ) * WW + (size_t)(gx * BSZ);

    if (tid < 128) bds[tid] = biasf[384 + tid];

    const f32x4 zero4 = {0.f, 0.f, 0.f, 0.f};

    for (int y0 = 0; y0 < 32; y0 += 4) {
        {
            const int px = tid & 31, chq = (tid >> 5) & 15;
#pragma unroll
            for (int j = 0; j < 4; ++j) {
                const float* sp = xb + (size_t)(chq * 4) * HW + (size_t)(y0 + j) * WW + px;
                float v0 = sp[0], v1 = sp[HW], v2 = sp[2 * HW], v3 = sp[3 * HW];
                *(uint2*)((char*)xs2[j] + SWZ128(px, chq * 4)) = pack4(v0, v1, v2, v3);
            }
        }
        __syncthreads();

        f32x4 cd[4][2];
#pragma unroll
        for (int m = 0; m < 4; ++m) { cd[m][0] = zero4; cd[m][1] = zero4; }
        const char* xrow = (const char*)xs2[wr];
#pragma unroll
        for (int ks = 0; ks < 2; ++ks) {
            const int kb = ks * 32 + lrow * 8;
            bf8_t a0 = *(const bf8_t*)(wdbf + (cb + 0  + lcol) * 64 + kb);
            bf8_t a1 = *(const bf8_t*)(wdbf + (cb + 16 + lcol) * 64 + kb);
            bf8_t a2 = *(const bf8_t*)(wdbf + (cb + 32 + lcol) * 64 + kb);
            bf8_t a3 = *(const bf8_t*)(wdbf + (cb + 48 + lcol) * 64 + kb);
            bf8_t b0 = *(const bf8_t*)(xrow + SWZ128(lcol, kb));
            bf8_t b1 = *(const bf8_t*)(xrow + SWZ128(lcol + 16, kb));
            cd[0][0] = MFMA(a0, b0, cd[0][0]);  cd[0][1] = MFMA(a0, b1, cd[0][1]);
            cd[1][0] = MFMA(a1, b0, cd[1][0]);  cd[1][1] = MFMA(a1, b1, cd[1][1]);
            cd[2][0] = MFMA(a2, b0, cd[2][0]);  cd[2][1] = MFMA(a2, b1, cd[2][1]);
            cd[3][0] = MFMA(a3, b0, cd[3][0]);  cd[3][1] = MFMA(a3, b1, cd[3][1]);
        }
        const int y = y0 + wr;
#pragma unroll
        for (int m = 0; m < 4; ++m) {
            const int ch = cb + m * 16 + lrow * 4;
            f32x4 bv = *(const f32x4*)&bds[ch];
#pragma unroll
            for (int nt = 0; nt < 2; ++nt) {
#pragma unroll
                for (int j = 0; j < 4; ++j) {
                    op[(size_t)(ch + j) * HW + (size_t)y * WW + nt * 16 + lcol] = cd[m][nt][j] + bv[j];
                }
            }
        }
        __syncthreads();
    }
}

extern "C" void kernel_launch(void* const* d_in, const int* in_sizes, int n_in,
                              void* d_out, int out_size, void* d_ws, size_t ws_size,
                              hipStream_t stream)
{
    const float* x   = (const float*)d_in[0];
    const int*   ind = (const int*)d_in[1];
    const float* w1  = (const float*)d_in[2];
    const float* b1  = (const float*)d_in[3];
    const float* w2  = (const float*)d_in[4];
    const float* b2  = (const float*)d_in[5];
    const float* w3  = (const float*)d_in[6];
    const float* b3  = (const float*)d_in[7];
    const float* wd  = (const float*)d_in[8];
    const float* bd  = (const float*)d_in[9];
    const float* g1  = (const float*)d_in[10];
    const float* be1 = (const float*)d_in[11];
    const float* m1  = (const float*)d_in[12];
    const float* v1  = (const float*)d_in[13];
    const float* g2  = (const float*)d_in[14];
    const float* be2 = (const float*)d_in[15];
    const float* m2  = (const float*)d_in[16];
    const float* v2  = (const float*)d_in[17];
    const float* g3  = (const float*)d_in[18];
    const float* be3 = (const float*)d_in[19];
    const float* m3  = (const float*)d_in[20];
    const float* v3  = (const float*)d_in[21];

    float* out = (float*)d_out;

    hipLaunchKernelGGL(k_prep, dim3(576), dim3(256), 0, stream,
                       w1, b1, w2, b2, w3, b3, wd, bd,
                       g1, be1, m1, v1, g2, be2, m2, v2, g3, be3, m3, v3, d_ws);
    hipLaunchKernelGGL(k_map, dim3(1), dim3(NBLK), 0, stream, ind, (int*)d_ws);
    hipLaunchKernelGGL(k_main, dim3(NBLK), dim3(512), 0, stream, x, ind, d_ws, out);
    hipLaunchKernelGGL(k_inactive, dim3(NCELL), dim3(512), 0, stream, x, d_ws, out);
}